// Round 1
// baseline (650.849 us; speedup 1.0000x reference)
//
#include <hip/hip_runtime.h>

typedef __bf16 bf16x8 __attribute__((ext_vector_type(8)));
typedef __bf16 bf16x4 __attribute__((ext_vector_type(4)));
typedef float  f32x4  __attribute__((ext_vector_type(4)));

#define NH    16
#define SEQ   8192
#define EDIM  64
#define CHK   512
#define WCOLS 15872      // 512 + 15*1024
#define OUT0  8388608    // NH*SEQ*EDIM

#define MFMA(a, b, c) __builtin_amdgcn_mfma_f32_16x16x32_bf16((a), (b), (c), 0, 0, 0)

// ---------------------------------------------------------------------------
// Kernel A: zero the masked half-windows (cols [n*1024, n*1024+512) for each
// h, n>=1). Fully-coalesced linear nt stores, runs at fill rate. 251.7 MB.
// ---------------------------------------------------------------------------
__global__ __launch_bounds__(256) void zero_fill_kernel(float* __restrict__ W) {
    const int gid = blockIdx.x * 256 + threadIdx.x;   // 524288 threads
    #pragma unroll
    for (int it = 0; it < 30; ++it) {                 // 524288*30 = 15728640 x4-units
        const int i     = gid + it * 524288;
        const int j     = i & 127;                    // x4-unit within 512-f32 row
        const int rowid = i >> 7;
        const int r     = rowid & 511;
        const int w     = rowid >> 9;                 // 0..239 = h*15 + (n-1)
        const int h     = w / 15;
        const int n     = w - h * 15 + 1;             // 1..15
        float* p = W + (size_t)(h * 512 + r) * WCOLS + (size_t)n * 1024 + j * 4;
        f32x4 z = {0.f, 0.f, 0.f, 0.f};
        __builtin_nontemporal_store(z, (f32x4*)p);
    }
}

// ---------------------------------------------------------------------------
// Kernel B: chunked attention. One block per (h, chunk). Computes S^T
// (MFMA operands swapped) so each lane owns one q-row with 4 consecutive
// key-cols per tile: f32x4 W stores, 2-shuffle softmax reductions, b64 LDS
// transpose writes. Q fragments hoisted before the loop so the mt loop has
// NO global loads -> no vmcnt waits -> stores never stall compute.
// ---------------------------------------------------------------------------
__global__ __launch_bounds__(512, 2) void chunked_attn_kernel(
    const float* __restrict__ Qg, const float* __restrict__ Kg,
    const float* __restrict__ Vg, float* __restrict__ out)
{
    // K frags (A-layout rows s): idx = ((t*2+es)*4 + quad)*16 + l16 -> 64 KB
    __shared__ __align__(16) __bf16 lds_k[32768];
    // V^T frags (B-layout): idx = ((st*4+nt)*4 + quad)*16 + l16 -> 64 KB
    __shared__ __align__(16) __bf16 lds_v[32768];
    // per-wave P transpose buffer, double-buffered: 16 rows x stride 40
    __shared__ __align__(16) __bf16 lds_p[8][2][640];

    const int tid  = threadIdx.x;
    const int lane = tid & 63;
    const int wv   = __builtin_amdgcn_readfirstlane(tid >> 6);  // SGPR-uniform
    const int l16  = lane & 15;
    const int quad = lane >> 4;     // 0..3

    const int h  = blockIdx.x >> 4;
    const int n  = blockIdx.x & 15;
    const int ns = (n == 0) ? 0 : n - 1;   // source chunk for K/V

    const size_t qbase = ((size_t)h * SEQ + (size_t)n  * CHK) * EDIM;
    const size_t kbase = ((size_t)h * SEQ + (size_t)ns * CHK) * EDIM;
    float* __restrict__ W = out + OUT0;
    const size_t wrow0   = (size_t)h * CHK;
    const int    colbase = (n == 0) ? 0 : (CHK + (n - 1) * 2 * CHK);

    const float SC = 0.125f * 1.44269504088896340736f;  // scale * log2(e), folded into Q

    // ---- hoisted Q fragments for all 4 mt tiles (B-layout: col q=l16,
    // k=e=quad*8+j). 32 VGPRs; removes all global loads from the main loop.
    bf16x8 aqf[4][2];
    #pragma unroll
    for (int mt = 0; mt < 4; ++mt) {
        const int m0 = mt * 128 + wv * 16;
        const float* qp = Qg + qbase + (size_t)(m0 + l16) * EDIM + quad * 8;
        float4 a = *(const float4*)(qp);
        float4 b = *(const float4*)(qp + 4);
        bf16x8 t0;
        t0[0]=(__bf16)(a.x*SC); t0[1]=(__bf16)(a.y*SC); t0[2]=(__bf16)(a.z*SC); t0[3]=(__bf16)(a.w*SC);
        t0[4]=(__bf16)(b.x*SC); t0[5]=(__bf16)(b.y*SC); t0[6]=(__bf16)(b.z*SC); t0[7]=(__bf16)(b.w*SC);
        aqf[mt][0] = t0;
        a = *(const float4*)(qp + 32);
        b = *(const float4*)(qp + 36);
        bf16x8 t1;
        t1[0]=(__bf16)(a.x*SC); t1[1]=(__bf16)(a.y*SC); t1[2]=(__bf16)(a.z*SC); t1[3]=(__bf16)(a.w*SC);
        t1[4]=(__bf16)(b.x*SC); t1[5]=(__bf16)(b.y*SC); t1[6]=(__bf16)(b.z*SC); t1[7]=(__bf16)(b.w*SC);
        aqf[mt][1] = t1;
    }

    // ---- stage K as bf16 frags: lane(quad,l16) of slot (t,sub) holds
    // K[s=t*16+l16][e=sub*8..+7] — valid as A-frag (rows s) AND B-frag.
    #pragma unroll
    for (int it = 0; it < 8; ++it) {
        const int c = tid + it * 512;          // 4096 chunks of 8 elems
        const int s = c >> 3, sub = c & 7;     // sub = es*4 + qd, e0 = sub*8
        const float* src = Kg + kbase + (size_t)s * EDIM + sub * 8;
        const float4 a = *(const float4*)src;
        const float4 b = *(const float4*)(src + 4);
        bf16x8 t;
        t[0] = (__bf16)a.x; t[1] = (__bf16)a.y; t[2] = (__bf16)a.z; t[3] = (__bf16)a.w;
        t[4] = (__bf16)b.x; t[5] = (__bf16)b.y; t[6] = (__bf16)b.z; t[7] = (__bf16)b.w;
        const int idx = ((s >> 4) * 8 + sub) * 16 + (s & 15);
        ((bf16x8*)lds_k)[idx] = t;
    }

    // ---- stage V^T as bf16 B-frags (coalesced reads along e) ----
    #pragma unroll
    for (int it = 0; it < 8; ++it) {
        const int c = tid + it * 512;
        const int e = c & 63, sb = c >> 6;     // sb = st*4 + qd, s0 = sb*8
        bf16x8 t;
        #pragma unroll
        for (int j = 0; j < 8; ++j)
            t[j] = (__bf16)Vg[kbase + (size_t)(sb * 8 + j) * EDIM + e];
        const int idx = (((sb >> 2) * 4 + (e >> 4)) * 4 + (sb & 3)) * 16 + (e & 15);
        ((bf16x8*)lds_v)[idx] = t;
    }

    __syncthreads();

    const bf16x8* const kf = (const bf16x8*)lds_k;
    const bf16x8* const vf = (const bf16x8*)lds_v;

    #pragma unroll
    for (int mt = 0; mt < 4; ++mt) {
        const int m0   = mt * 128 + wv * 16;   // interleaved: balances triangular work
        const int tmax = mt * 8 + wv;          // last s-tile with any unmasked col (SGPR)
        const int qrow = m0 + l16;             // this lane's q-row (lane owns one row)

        // ---- S^T tiles: MFMA(K as A, Q as B) -> D[s][q]; lane(quad,l16):
        // q = l16, s = t*16 + quad*4 + r  (4 CONSECUTIVE key-cols per reg) ----
        f32x4 st[32];
        #pragma unroll
        for (int t = 0; t < 32; ++t) {
            if (t <= tmax) {                   // uniform SGPR branch: skip masked tiles
                const int kb = t * 128 + quad * 16 + l16;
                f32x4 acc = {0.f, 0.f, 0.f, 0.f};
                acc = MFMA(kf[kb],      aqf[mt][0], acc);
                acc = MFMA(kf[kb + 64], aqf[mt][1], acc);
                const int sb = t * 16 + quad * 4;
                #pragma unroll
                for (int r = 0; r < 4; ++r)
                    acc[r] = (sb + r <= qrow) ? acc[r] : -3.0e38f;
                st[t] = acc;
            } else {
                st[t] = (f32x4){0.f, 0.f, 0.f, 0.f};   // stored as exact zeros
            }
        }

        // ---- row max: in-lane over 128 vals, then 2 shuffles across quads ----
        float mr = -3.0e38f;
        #pragma unroll
        for (int t = 0; t < 32; ++t) {
            if (t <= tmax) {
                #pragma unroll
                for (int r = 0; r < 4; ++r) mr = fmaxf(mr, st[t][r]);
            }
        }
        mr = fmaxf(mr, __shfl_xor(mr, 16));
        mr = fmaxf(mr, __shfl_xor(mr, 32));

        // ---- exp2 + row sum (masked -> exp2(-3e38 - mr) == 0 exactly) ----
        float lr = 0.f;
        #pragma unroll
        for (int t = 0; t < 32; ++t) {
            if (t <= tmax) {
                #pragma unroll
                for (int r = 0; r < 4; ++r) {
                    const float e = __builtin_amdgcn_exp2f(st[t][r] - mr);
                    st[t][r] = e;
                    lr += e;
                }
            }
        }
        lr += __shfl_xor(lr, 16);
        lr += __shfl_xor(lr, 32);
        const float ri = __builtin_amdgcn_rcpf(lr);

        // ---- normalize in place (zero tiles stay zero) ----
        #pragma unroll
        for (int t = 0; t < 32; ++t) {
            if (t <= tmax) st[t] = st[t] * ri;
        }

        // ---- W store: one f32x4 per tile, full precision. Per instr: 16 rows
        // x 64 B contiguous. Fire-and-forget; no loads follow in this loop, so
        // no vmcnt wait ever blocks on the drain. ----
        {
            float* const wp = W + (wrow0 + (size_t)qrow) * WCOLS + colbase + quad * 4;
            #pragma unroll
            for (int t = 0; t < 32; ++t)
                __builtin_nontemporal_store(st[t], (f32x4*)(wp + t * 16));
        }

        // ---- PV: transpose P rows into A-frags via per-wave LDS (double-
        // buffered to break the WAR chain), skip all-zero s-blocks. ----
        f32x4 o0 = {0,0,0,0}, o1 = {0,0,0,0}, o2 = {0,0,0,0}, o3 = {0,0,0,0};
        #pragma unroll
        for (int pr = 0; pr < 16; ++pr) {
            if (2 * pr <= tmax) {              // uniform branch: P==0 beyond tmax
                __bf16* const pbuf = lds_p[wv][pr & 1];
                #pragma unroll
                for (int tt = 0; tt < 2; ++tt) {
                    const int t = pr * 2 + tt;
                    bf16x4 w;
                    #pragma unroll
                    for (int r = 0; r < 4; ++r) w[r] = (__bf16)st[t][r];
                    // row q=l16, cols tt*16+quad*4..+3 (one ds_write_b64)
                    *(bf16x4*)(pbuf + l16 * 40 + tt * 16 + quad * 4) = w;
                }
                // A-frag read: row l16, k = quad*8..+7 (in-wave DS ordering)
                const bf16x8 pa = *(const bf16x8*)(pbuf + l16 * 40 + quad * 8);
                const int vb = pr * 256 + quad * 16 + l16;
                o0 = MFMA(pa, vf[vb      ], o0);
                o1 = MFMA(pa, vf[vb +  64], o1);
                o2 = MFMA(pa, vf[vb + 128], o2);
                o3 = MFMA(pa, vf[vb + 192], o3);
            }
        }

        // ---- write O tile (C-layout rows = m0 + quad*4 + r, col l16) ----
        const int rq = m0 + quad * 4;
        const size_t ob = qbase + (size_t)rq * EDIM + l16;
        #pragma unroll
        for (int r = 0; r < 4; ++r) {
            __builtin_nontemporal_store(o0[r], out + ob + (size_t)r * EDIM     );
            __builtin_nontemporal_store(o1[r], out + ob + (size_t)r * EDIM + 16);
            __builtin_nontemporal_store(o2[r], out + ob + (size_t)r * EDIM + 32);
            __builtin_nontemporal_store(o3[r], out + ob + (size_t)r * EDIM + 48);
        }
    }
}

extern "C" void kernel_launch(void* const* d_in, const int* in_sizes, int n_in,
                              void* d_out, int out_size, void* d_ws, size_t ws_size,
                              hipStream_t stream) {
    const float* Q = (const float*)d_in[0];
    const float* K = (const float*)d_in[1];
    const float* V = (const float*)d_in[2];
    float* out = (float*)d_out;
    zero_fill_kernel<<<dim3(2048), dim3(256), 0, stream>>>(out + OUT0);
    chunked_attn_kernel<<<dim3(256), dim3(512), 0, stream>>>(Q, K, V, out);
}